// Round 10
// baseline (254.659 us; speedup 1.0000x reference)
//
#include <hip/hip_runtime.h>
#include <hip/hip_bf16.h>

#define NH   16
#define HD   64
#define HID  1024
#define TSEQ 2048
#define BATCH 2
#define KSCALE 0.18033688011112042f   // 0.125 * log2(e), folded into Wk/bk

typedef __attribute__((ext_vector_type(4))) float f32x4;
typedef __attribute__((ext_vector_type(8))) short s16x8;
typedef __attribute__((ext_vector_type(4))) short s16x4;
typedef __attribute__((ext_vector_type(8))) _Float16 f16x8;
typedef __attribute__((ext_vector_type(4))) _Float16 f16x4;
typedef __attribute__((ext_vector_type(2))) _Float16 f16x2;

__device__ __forceinline__ unsigned short f2bf(float f) {
  union { float f; unsigned int u; } v; v.f = f;
  unsigned int r = v.u + 0x7fffu + ((v.u >> 16) & 1u);
  return (unsigned short)(r >> 16);
}
__device__ __forceinline__ float bf2f(unsigned short b) {
  union { unsigned int u; float f; } v; v.u = ((unsigned int)b) << 16; return v.f;
}

// async global->LDS, 16B per lane; LDS dest must be wave-uniform base (+lane*16 by HW)
__device__ __forceinline__ void gll16(const void* g, void* l) {
  __builtin_amdgcn_global_load_lds(
      (const __attribute__((address_space(1))) unsigned int*)g,
      (__attribute__((address_space(3))) unsigned int*)l, 16, 0, 0);
}

// counted-vmcnt barrier: own-wave outstanding loads <= N, then collective barrier.
#define WAITBAR(N)                                                      \
  do {                                                                  \
    __builtin_amdgcn_sched_barrier(0);                                  \
    asm volatile("s_waitcnt vmcnt(" #N ")\n\ts_barrier" ::: "memory");  \
  } while (0)

// ---------------- one cast kernel: h + all 4 weights (Wk pre-scaled) ----------------
__global__ __launch_bounds__(256) void cast_all_k(
    const float* __restrict__ h,
    const float* __restrict__ w0, const float* __restrict__ w1,
    const float* __restrict__ w2, const float* __restrict__ w3,
    unsigned short* __restrict__ hb, unsigned short* __restrict__ wbase) {
  int i = blockIdx.x * 256 + threadIdx.x;  // 2097152 float4 total
  const float* src; unsigned short* dst; int idx; float sc = 1.f;
  if (i < 1048576) { src = h; dst = hb; idx = i; }
  else {
    int idx4 = i - 1048576;
    int w = idx4 >> 18;
    idx = idx4 & 262143;
    src = (w == 0) ? w0 : (w == 1) ? w1 : (w == 2) ? w2 : w3;
    dst = wbase + (size_t)(idx4 - idx) * 4;   // contiguous weight region
    if (w == 1) sc = KSCALE;
  }
  float4 v = ((const float4*)src)[idx];
  ushort4 o;
  o.x = f2bf(v.x * sc); o.y = f2bf(v.y * sc); o.z = f2bf(v.z * sc); o.w = f2bf(v.w * sc);
  ((ushort4*)dst)[idx] = o;
}

// ---------------- Fused QKV projection: one 4096x3072x1024 NT-GEMM ----------------
// 128x192 tile -> grid 512 = exactly 2 blocks/CU (no tail), ring-4 LDS (80 KB),
// prefetch distance 3, counted vmcnt (never 0 in main loop).  [R8-proven]
__global__ __launch_bounds__(256) void gemm_qkv(
    const unsigned short* __restrict__ hb,
    const unsigned short* __restrict__ wcat,   // [3072][1024] = Wq|Wk|Wv, Wk pre-scaled
    const float* __restrict__ bq, const float* __restrict__ bk, const float* __restrict__ bv,
    unsigned short* __restrict__ qo, unsigned short* __restrict__ ko,
    unsigned short* __restrict__ vto) {
  __shared__ unsigned short Ash[4][128 * 32];   // 4 x 8 KB
  __shared__ unsigned short Bsh[4][192 * 32];   // 4 x 12 KB  (total 80 KB -> 2 blocks/CU)
  const int tid = threadIdx.x, lane = tid & 63, wave = tid >> 6;
  const int l15 = lane & 15, quad = lane >> 4;
  const int wr = wave >> 1, wc = wave & 1;      // 2x2 waves, each 64x96 out
  const int bn = blockIdx.x * 192, bm = blockIdx.y * 128;
  const char* Ab = (const char*)(hb + (size_t)bm * HID);
  const char* Bb = (const char*)(wcat + (size_t)bn * HID);
  // staging: A tile [128 r][32 k] = 8 KB (2 issues), B tile [192 r][32 k] = 12 KB (3 issues)
  const int off = tid * 16;                 // byte offset within one 4 KB issue
  const int r0 = off >> 6, c0 = off & 63;   // 64 B per tile row
  const size_t ga0 = (size_t)r0 * (HID * 2) + c0;
  const size_t ga1 = ga0 + (size_t)64  * (HID * 2);
  const size_t gb2 = ga0 + (size_t)128 * (HID * 2);
  const int lb0 = wave * 512;               // LDS dest (elements); HW adds lane*16B
  const int lb1 = 2048 + wave * 512;
  const int lb2 = 4096 + wave * 512;

  f32x4 acc[4][6];
#pragma unroll
  for (int i = 0; i < 4; ++i)
#pragma unroll
    for (int j = 0; j < 6; ++j) acc[i][j] = f32x4{0.f, 0.f, 0.f, 0.f};

  auto stage = [&](int bufi, int k0) {      // 5 loads per thread per tile
    const size_t kb = (size_t)k0 * 2;
    gll16(Ab + ga0 + kb, &Ash[bufi][lb0]);
    gll16(Ab + ga1 + kb, &Ash[bufi][lb1]);
    gll16(Bb + ga0 + kb, &Bsh[bufi][lb0]);
    gll16(Bb + ga1 + kb, &Bsh[bufi][lb1]);
    gll16(Bb + gb2 + kb, &Bsh[bufi][lb2]);
  };
  auto compute = [&](int bufi) {
    s16x8 af[4], bfr[6];
#pragma unroll
    for (int i = 0; i < 4; ++i)
      af[i] = *(const s16x8*)(&Ash[bufi][(wr * 64 + i * 16 + l15) * 32 + quad * 8]);
#pragma unroll
    for (int j = 0; j < 6; ++j)
      bfr[j] = *(const s16x8*)(&Bsh[bufi][(wc * 96 + j * 16 + l15) * 32 + quad * 8]);
#pragma unroll
    for (int i = 0; i < 4; ++i)
#pragma unroll
      for (int j = 0; j < 6; ++j)
        acc[i][j] = __builtin_amdgcn_mfma_f32_16x16x32_bf16(af[i], bfr[j], acc[i][j], 0, 0, 0);
  };

  // prologue: tiles 0..2 in flight (15 outstanding/wave)
  stage(0, 0);
  stage(1, 32);
  stage(2, 64);
  int cur = 0, pf = 3;
  const int NT = HID / 32;                  // 32
  for (int t = 0; t < NT - 3; ++t) {        // t = 0..28
    WAITBAR(10);                            // tile t landed; t+1,t+2 stay in flight
    stage(pf, (t + 3) * 32);
    compute(cur);
    cur = (cur + 1) & 3;
    pf  = (pf + 1) & 3;
  }
  WAITBAR(10); compute(cur); cur = (cur + 1) & 3;   // t = NT-3
  WAITBAR(5);  compute(cur); cur = (cur + 1) & 3;   // t = NT-2
  WAITBAR(0);  compute(cur);                        // t = NT-1

  // epilogue: 16-col groups never straddle a 1024 boundary -> mat uniform per j
  const int rbase = bm + wr * 64;
#pragma unroll
  for (int j = 0; j < 6; ++j) {
    const int cg  = bn + wc * 96 + j * 16;  // group start (multiple of 16)
    const int mat = cg >> 10;               // 0=Q 1=K 2=V
    const int coln = (cg & 1023) + l15;     // column within matrix
    const int head = coln >> 6, d = coln & 63;
    if (mat == 2) {
      // V: f16, transposed [B,NH,D,T]; 4 consecutive t per lane = 8B store
      const float bb = bv[coln];
#pragma unroll
      for (int i = 0; i < 4; ++i) {
        const int row0 = rbase + i * 16 + quad * 4;
        const int bI = row0 >> 11, t0 = row0 & 2047;
        unsigned short o[4];
#pragma unroll
        for (int r = 0; r < 4; ++r) {
          _Float16 hv = (_Float16)(acc[i][j][r] + bb);
          o[r] = __builtin_bit_cast(unsigned short, hv);
        }
        *(s16x4*)(vto + ((size_t)((bI * NH + head) * HD + d)) * TSEQ + t0) = *(const s16x4*)o;
      }
    } else {
      unsigned short* dst = (mat == 0) ? qo : ko;
      const float bb = (mat == 0) ? bq[coln] : bk[coln] * KSCALE;
#pragma unroll
      for (int i = 0; i < 4; ++i) {
#pragma unroll
        for (int r = 0; r < 4; ++r) {
          const int row = rbase + i * 16 + quad * 4 + r;
          const int bI = row >> 11, t = row & 2047;
          dst[(((size_t)(bI * NH + head) * TSEQ) + t) * HD + d] = f2bf(acc[i][j][r] + bb);
        }
      }
    }
  }
}

// ---------------- Output projection: 128x64 tile, 5-ring depth-4 ----------------
__global__ __launch_bounds__(256) void gemm_out(
    const unsigned short* __restrict__ ctx, const unsigned short* __restrict__ wo,
    const float* __restrict__ bo, const float* __restrict__ hres,
    float* __restrict__ outf) {
  __shared__ unsigned short Ash[5][128 * 32];   // 5 x 8 KB
  __shared__ unsigned short Bsh[5][64 * 32];    // 5 x 4 KB  (total 60 KB)
  const int tid = threadIdx.x, lane = tid & 63, wave = tid >> 6;
  const int l15 = lane & 15, quad = lane >> 4;
  const int wr = wave >> 1, wc = wave & 1;      // each wave: 64 rows x 32 cols
  const int bn = blockIdx.x * 64, bm = blockIdx.y * 128;
  const char* Ab = (const char*)(ctx + (size_t)bm * HID);
  const char* Bb = (const char*)(wo + (size_t)bn * HID);
  const int off = tid * 16;
  const int r0 = off >> 6, c0 = off & 63;
  const size_t ga0 = (size_t)r0 * (HID * 2) + c0;
  const size_t ga1 = ga0 + (size_t)64 * (HID * 2);
  const int lb0 = wave * 512, lb1 = 2048 + wave * 512;

  f32x4 acc[4][2];
#pragma unroll
  for (int i = 0; i < 4; ++i)
#pragma unroll
    for (int j = 0; j < 2; ++j) acc[i][j] = f32x4{0.f, 0.f, 0.f, 0.f};

  auto stage = [&](int bufi, int k0) {
    const size_t kb = (size_t)k0 * 2;
    gll16(Ab + ga0 + kb, &Ash[bufi][lb0]);
    gll16(Ab + ga1 + kb, &Ash[bufi][lb1]);
    gll16(Bb + ga0 + kb, &Bsh[bufi][lb0]);   // 64x32 B-tile = exactly one issue
  };
  auto compute = [&](int bufi) {
    s16x8 af[4], bfr[2];
#pragma unroll
    for (int i = 0; i < 4; ++i)
      af[i] = *(const s16x8*)(&Ash[bufi][(wr * 64 + i * 16 + l15) * 32 + quad * 8]);
#pragma unroll
    for (int j = 0; j < 2; ++j)
      bfr[j] = *(const s16x8*)(&Bsh[bufi][(wc * 32 + j * 16 + l15) * 32 + quad * 8]);
#pragma unroll
    for (int i = 0; i < 4; ++i)
#pragma unroll
      for (int j = 0; j < 2; ++j)
        acc[i][j] = __builtin_amdgcn_mfma_f32_16x16x32_bf16(af[i], bfr[j], acc[i][j], 0, 0, 0);
  };

  stage(0, 0);
  stage(1, 32);
  stage(2, 64);
  stage(3, 96);
  int cur = 0, pf = 4;
  const int NT = HID / 32;
  for (int t = 0; t < NT - 4; ++t) {
    WAITBAR(9);                             // 3 loads/tile: tile t home, 3 tiles in flight
    stage(pf, (t + 4) * 32);
    compute(cur);
    cur = (cur == 4) ? 0 : cur + 1;
    pf  = (pf  == 4) ? 0 : pf + 1;
  }
  WAITBAR(9); compute(cur); cur = (cur == 4) ? 0 : cur + 1;    // t = NT-4
  WAITBAR(6); compute(cur); cur = (cur == 4) ? 0 : cur + 1;    // t = NT-3
  WAITBAR(3); compute(cur); cur = (cur == 4) ? 0 : cur + 1;    // t = NT-2
  WAITBAR(0); compute(cur);                                    // t = NT-1

#pragma unroll
  for (int j = 0; j < 2; ++j) {
    const int col = bn + wc * 32 + j * 16 + l15;
    const float bb = bo[col];
#pragma unroll
    for (int i = 0; i < 4; ++i) {
#pragma unroll
      for (int r = 0; r < 4; ++r) {
        const int row = bm + wr * 64 + i * 16 + quad * 4 + r;
        const size_t o = (size_t)row * HID + col;
        outf[o] = acc[i][j][r] + bb + hres[o];
      }
    }
  }
}

// ---------------- Flash attention: S^T form, K=32 PV, 2-buffer / 2-barrier, 4 blocks/CU ----------------
// 36 KB LDS -> 4 blocks/CU = 16 waves/CU (was 2 blocks, 17% occupancy, ~40% stall).
// Per iter: sync; wlds(t+1); sync; ldregs(t+2); QK^T(t+1); PV(t); exp(t+1).
// rsum via ones-row MFMA. setprio(1) around MFMA clusters (T5).
__global__ __launch_bounds__(256, 4) void attn_k(
    const unsigned short* __restrict__ qb, const unsigned short* __restrict__ kb,
    const unsigned short* __restrict__ vt, unsigned short* __restrict__ ctx,
    int ntiles) {
  __shared__ unsigned short Ksh[2][64 * 72];   // bf16 [key][d], double buffer
  __shared__ unsigned short Vsh[2][64 * 72];   // f16  [d][key-permuted], double buffer

  const int tid = threadIdx.x, lane = tid & 63, wave = tid >> 6;
  const int l15 = lane & 15, quad = lane >> 4;
  const int b = blockIdx.z;
  const int h = blockIdx.y, qt = blockIdx.x;
  const size_t ho = ((size_t)(b * NH + h)) * TSEQ * HD;
  const unsigned short* Qh = qb + ho;
  const unsigned short* Kh = kb + ho;
  const unsigned short* Vh = vt + ho;
  const int q0 = qt * 128 + wave * 32;

  s16x8 qf[2][2];
#pragma unroll
  for (int s = 0; s < 2; ++s)
#pragma unroll
    for (int ks = 0; ks < 2; ++ks)
      qf[s][ks] = *(const s16x8*)(Qh + (size_t)(q0 + s * 16 + l15) * HD + ks * 32 + quad * 8);

  f32x4 accO[4][2];   // O^T: [d-strip n2][q-col s], lane=(d=quad*4+r, q=l15)
  f32x4 accR[2];      // ones-row PV: every lane ends with full key-sum for q=l15
#pragma unroll
  for (int n2 = 0; n2 < 4; ++n2)
#pragma unroll
    for (int s = 0; s < 2; ++s) accO[n2][s] = f32x4{0.f, 0.f, 0.f, 0.f};
  accR[0] = accR[1] = f32x4{0.f, 0.f, 0.f, 0.f};
  const f16x8 vones = {(_Float16)1.f, (_Float16)1.f, (_Float16)1.f, (_Float16)1.f,
                       (_Float16)1.f, (_Float16)1.f, (_Float16)1.f, (_Float16)1.f};

  const int sr = tid >> 3, sc = (tid & 7) * 8;
  // V permuted write base: c = key-chunk index 0..7, keys 8c..8c+7 ->
  // two 4-key runs at vwb and vwb+8 (verified element-wise, R6-passing)
  const int c = tid & 7;
  const int vwb = (c >> 2) * 32 + (c & 1) * 16 + ((c & 3) >> 1) * 4;
  s16x8 kreg[2], vreg[2];

  auto ldregs = [&](int kt) {
    const int k0n = kt * 64;
#pragma unroll
    for (int hf = 0; hf < 2; ++hf) {
      kreg[hf] = *(const s16x8*)(Kh + (size_t)(k0n + sr + hf * 32) * HD + sc);
      vreg[hf] = *(const s16x8*)(Vh + (size_t)(sr + hf * 32) * TSEQ + k0n + sc);
    }
  };
  auto wlds = [&](int bi) {
#pragma unroll
    for (int hf = 0; hf < 2; ++hf) {
      *(s16x8*)(Ksh[bi] + (sr + hf * 32) * 72 + sc) = kreg[hf];
      const s16x4* vh = (const s16x4*)&vreg[hf];
      *(s16x4*)(Vsh[bi] + (sr + hf * 32) * 72 + vwb)     = vh[0];
      *(s16x4*)(Vsh[bi] + (sr + hf * 32) * 72 + vwb + 8) = vh[1];
    }
  };

  f32x4 accS[2][4];
  f16x4 pP[2][4];

  auto qkt = [&](int bi) {
#pragma unroll
    for (int s = 0; s < 2; ++s)
#pragma unroll
      for (int n = 0; n < 4; ++n) accS[s][n] = f32x4{0.f, 0.f, 0.f, 0.f};
    __builtin_amdgcn_s_setprio(1);
#pragma unroll
    for (int ks = 0; ks < 2; ++ks) {
#pragma unroll
      for (int n = 0; n < 4; ++n) {
        s16x8 kf = *(const s16x8*)(Ksh[bi] + (n * 16 + l15) * 72 + ks * 32 + quad * 8);
#pragma unroll
        for (int s = 0; s < 2; ++s)
          accS[s][n] = __builtin_amdgcn_mfma_f32_16x16x32_bf16(kf, qf[s][ks], accS[s][n], 0, 0, 0);
      }
    }
    __builtin_amdgcn_s_setprio(0);
  };
  auto expp = [&]() {   // accS -> pP (f16 pairs); rsum handled by ones-row MFMA
#pragma unroll
    for (int s = 0; s < 2; ++s)
#pragma unroll
      for (int n = 0; n < 4; ++n) {
        float e0 = __builtin_amdgcn_exp2f(accS[s][n][0]);
        float e1 = __builtin_amdgcn_exp2f(accS[s][n][1]);
        float e2 = __builtin_amdgcn_exp2f(accS[s][n][2]);
        float e3 = __builtin_amdgcn_exp2f(accS[s][n][3]);
        f16x2 lo = __builtin_bit_cast(f16x2, __builtin_amdgcn_cvt_pkrtz(e0, e1));
        f16x2 hi = __builtin_bit_cast(f16x2, __builtin_amdgcn_cvt_pkrtz(e2, e3));
        pP[s][n] = f16x4{lo[0], lo[1], hi[0], hi[1]};
      }
  };
  auto pv = [&](int bi) {   // K=32 full-rate f16 MFMA + ones-row rsum
    __builtin_amdgcn_s_setprio(1);
#pragma unroll
    for (int kk = 0; kk < 2; ++kk) {
      union { f16x4 h[2]; f16x8 v8; } u0, u1;
      u0.h[0] = pP[0][2 * kk]; u0.h[1] = pP[0][2 * kk + 1];
      u1.h[0] = pP[1][2 * kk]; u1.h[1] = pP[1][2 * kk + 1];
      accR[0] = __builtin_amdgcn_mfma_f32_16x16x32_f16(vones, u0.v8, accR[0], 0, 0, 0);
      accR[1] = __builtin_amdgcn_mfma_f32_16x16x32_f16(vones, u1.v8, accR[1], 0, 0, 0);
#pragma unroll
      for (int n2 = 0; n2 < 4; ++n2) {
        f16x8 vA = *(const f16x8*)(Vsh[bi] + (n2 * 16 + l15) * 72 + kk * 32 + quad * 8);
        accO[n2][0] = __builtin_amdgcn_mfma_f32_16x16x32_f16(vA, u0.v8, accO[n2][0], 0, 0, 0);
        accO[n2][1] = __builtin_amdgcn_mfma_f32_16x16x32_f16(vA, u1.v8, accO[n2][1], 0, 0, 0);
      }
    }
    __builtin_amdgcn_s_setprio(0);
  };

  // prologue
  ldregs(0);
  wlds(0);
  __syncthreads();
  if (ntiles > 1) ldregs(1);
  qkt(0);
  expp();

  for (int t = 0; t < ntiles - 1; ++t) {
    const int b0 = t & 1, b1 = (t + 1) & 1;
    __syncthreads();              // pv(t-1) readers done with buffer b1
    wlds(b1);                     // stage tile t+1 (regs loaded at iter t-1)
    __syncthreads();              // writes visible to all waves
    if (t + 2 < ntiles) ldregs(t + 2);
    qkt(b1);                      // accS(t+1)  [MFMA]
    pv(b0);                       // PV(t) w/ pP(t) [MFMA] - independent of accS
    expp();                       // exp(t+1) -> pP [VALU] - overlaps PV issue
  }
  pv((ntiles - 1) & 1);           // PV(ntiles-1)

  float rsum[2] = {accR[0][0], accR[1][0]};   // all lanes hold their q's full sum

#pragma unroll
  for (int s = 0; s < 2; ++s) {
    const int t = q0 + s * 16 + l15;
    const float inv = 1.f / rsum[s];
#pragma unroll
    for (int n2 = 0; n2 < 4; ++n2) {
      const int d0 = n2 * 16 + quad * 4;
      unsigned short o[4];
#pragma unroll
      for (int r = 0; r < 4; ++r) o[r] = f2bf(accO[n2][s][r] * inv);
      *(s16x4*)(ctx + ((size_t)(b * TSEQ + t)) * HID + h * HD + d0) = *(const s16x4*)o;
    }
  }
}

// ---------------- In-place LayerNorm over rows of 1024 ----------------
__global__ __launch_bounds__(256) void ln_k(float* __restrict__ io,
                                            const float* __restrict__ gamma,
                                            const float* __restrict__ beta) {
  const int row = blockIdx.x, tid = threadIdx.x;
  float x[4]; float s = 0.f, s2 = 0.f;
#pragma unroll
  for (int i = 0; i < 4; ++i) {
    x[i] = io[(size_t)row * HID + tid + i * 256];
    s += x[i]; s2 += x[i] * x[i];
  }
#pragma unroll
  for (int off = 1; off < 64; off <<= 1) {
    s  += __shfl_xor(s, off, 64);
    s2 += __shfl_xor(s2, off, 64);
  }
  __shared__ float red[8];
  const int wave = tid >> 6;
  if ((tid & 63) == 0) { red[wave] = s; red[wave + 4] = s2; }
  __syncthreads();
  s  = red[0] + red[1] + red[2] + red[3];
  s2 = red[4] + red[5] + red[6] + red[7];
  const float mean = s * (1.f / HID);
  const float var  = s2 * (1.f / HID) - mean * mean;
  const float rstd = rsqrtf(var + 1e-6f);
#pragma unroll
  for (int i = 0; i < 4; ++i) {
    const int col = tid + i * 256;
    io[(size_t)row * HID + col] = (x[i] - mean) * rstd * gamma[col] + beta[col];
  }
}

extern "C" void kernel_launch(void* const* d_in, const int* in_sizes, int n_in,
                              void* d_out, int out_size, void* d_ws, size_t ws_size,
                              hipStream_t stream) {
  const float* h    = (const float*)d_in[0];
  const float* Wq   = (const float*)d_in[1];
  const float* bq   = (const float*)d_in[2];
  const float* Wk   = (const float*)d_in[3];
  const float* bk   = (const float*)d_in[4];
  const float* Wv   = (const float*)d_in[5];
  const float* bv   = (const float*)d_in[6];
  const float* Wo   = (const float*)d_in[7];
  const float* bo   = (const float*)d_in[8];
  const float* gamma = (const float*)d_in[9];
  const float* beta  = (const float*)d_in[10];
  float* out = (float*)d_out;

  unsigned short* hb   = (unsigned short*)d_ws;   // bf16 h; dead after gemm_qkv -> reused as ctx
  unsigned short* wqb  = hb  + 4194304;           // 4 weights contiguous (Wq|Wk|Wv|Wo)
  unsigned short* wkb  = wqb + 1048576;
  unsigned short* wvb  = wkb + 1048576;
  unsigned short* wob  = wvb + 1048576;
  unsigned short* qb   = wob + 1048576;           // bf16 [B,NH,T,D]
  unsigned short* kb   = qb  + 4194304;
  unsigned short* vtf  = kb  + 4194304;           // f16 [B,NH,D,T], written by gemm_qkv directly
  unsigned short* ctxb = hb;                      // ctx aliases dead hb

  cast_all_k<<<8192, 256, 0, stream>>>(h, Wq, Wk, Wv, Wo, hb, wqb);
  gemm_qkv<<<dim3(16, 32), 256, 0, stream>>>(hb, wqb, bq, bk, bv, qb, kb, vtf);
  attn_k<<<dim3(TSEQ / 128, NH, BATCH), 256, 0, stream>>>(qb, kb, vtf, ctxb, 32);
  gemm_out<<<dim3(16, 32), 256, 0, stream>>>(ctxb, wob, bo, h, out);
  ln_k<<<4096, 256, 0, stream>>>(out, gamma, beta);
}

// Round 11
// 199.307 us; speedup vs baseline: 1.2777x; 1.2777x over previous
//
#include <hip/hip_runtime.h>
#include <hip/hip_bf16.h>

#define NH   16
#define HD   64
#define HID  1024
#define TSEQ 2048
#define BATCH 2
#define KSCALE 0.18033688011112042f   // 0.125 * log2(e), folded into Wk/bk

typedef __attribute__((ext_vector_type(4))) float f32x4;
typedef __attribute__((ext_vector_type(8))) short s16x8;
typedef __attribute__((ext_vector_type(4))) short s16x4;
typedef __attribute__((ext_vector_type(8))) _Float16 f16x8;
typedef __attribute__((ext_vector_type(4))) _Float16 f16x4;
typedef __attribute__((ext_vector_type(2))) _Float16 f16x2;

__device__ __forceinline__ unsigned short f2bf(float f) {
  union { float f; unsigned int u; } v; v.f = f;
  unsigned int r = v.u + 0x7fffu + ((v.u >> 16) & 1u);
  return (unsigned short)(r >> 16);
}
__device__ __forceinline__ float bf2f(unsigned short b) {
  union { unsigned int u; float f; } v; v.u = ((unsigned int)b) << 16; return v.f;
}

// async global->LDS, 16B per lane; LDS dest must be wave-uniform base (+lane*16 by HW)
__device__ __forceinline__ void gll16(const void* g, void* l) {
  __builtin_amdgcn_global_load_lds(
      (const __attribute__((address_space(1))) unsigned int*)g,
      (__attribute__((address_space(3))) unsigned int*)l, 16, 0, 0);
}

// counted-vmcnt barrier: own-wave outstanding loads <= N, then collective barrier.
#define WAITBAR(N)                                                      \
  do {                                                                  \
    __builtin_amdgcn_sched_barrier(0);                                  \
    asm volatile("s_waitcnt vmcnt(" #N ")\n\ts_barrier" ::: "memory");  \
  } while (0)

// ---------------- one cast kernel: h + all 4 weights (Wk pre-scaled) ----------------
__global__ __launch_bounds__(256) void cast_all_k(
    const float* __restrict__ h,
    const float* __restrict__ w0, const float* __restrict__ w1,
    const float* __restrict__ w2, const float* __restrict__ w3,
    unsigned short* __restrict__ hb, unsigned short* __restrict__ wbase) {
  int i = blockIdx.x * 256 + threadIdx.x;  // 2097152 float4 total
  const float* src; unsigned short* dst; int idx; float sc = 1.f;
  if (i < 1048576) { src = h; dst = hb; idx = i; }
  else {
    int idx4 = i - 1048576;
    int w = idx4 >> 18;
    idx = idx4 & 262143;
    src = (w == 0) ? w0 : (w == 1) ? w1 : (w == 2) ? w2 : w3;
    dst = wbase + (size_t)(idx4 - idx) * 4;   // contiguous weight region
    if (w == 1) sc = KSCALE;
  }
  float4 v = ((const float4*)src)[idx];
  ushort4 o;
  o.x = f2bf(v.x * sc); o.y = f2bf(v.y * sc); o.z = f2bf(v.z * sc); o.w = f2bf(v.w * sc);
  ((ushort4*)dst)[idx] = o;
}

// ---------------- Fused QKV projection: one 4096x3072x1024 NT-GEMM ----------------
// 128x192 tile -> grid 512 = exactly 2 blocks/CU, ring-4 LDS (80 KB), prefetch
// distance 3, counted vmcnt. XCD-chunked block swizzle (T1, bijective: 512%8==0).
__global__ __launch_bounds__(256) void gemm_qkv(
    const unsigned short* __restrict__ hb,
    const unsigned short* __restrict__ wcat,   // [3072][1024] = Wq|Wk|Wv, Wk pre-scaled
    const float* __restrict__ bq, const float* __restrict__ bk, const float* __restrict__ bv,
    unsigned short* __restrict__ qo, unsigned short* __restrict__ ko,
    unsigned short* __restrict__ vto) {
  __shared__ unsigned short Ash[4][128 * 32];   // 4 x 8 KB
  __shared__ unsigned short Bsh[4][192 * 32];   // 4 x 12 KB  (total 80 KB -> 2 blocks/CU)
  const int tid = threadIdx.x, lane = tid & 63, wave = tid >> 6;
  const int l15 = lane & 15, quad = lane >> 4;
  const int wr = wave >> 1, wc = wave & 1;      // 2x2 waves, each 64x96 out
  // XCD-chunked swizzle: each XCD gets 64 consecutive work-items (4 A-panels, L2-resident)
  const int bid = blockIdx.y * 16 + blockIdx.x;       // 0..511
  const int swz = (bid & 7) * 64 + (bid >> 3);
  const int bn = (swz & 15) * 192, bm = (swz >> 4) * 128;
  const char* Ab = (const char*)(hb + (size_t)bm * HID);
  const char* Bb = (const char*)(wcat + (size_t)bn * HID);
  // staging: A tile [128 r][32 k] = 8 KB (2 issues), B tile [192 r][32 k] = 12 KB (3 issues)
  const int off = tid * 16;                 // byte offset within one 4 KB issue
  const int r0 = off >> 6, c0 = off & 63;   // 64 B per tile row
  const size_t ga0 = (size_t)r0 * (HID * 2) + c0;
  const size_t ga1 = ga0 + (size_t)64  * (HID * 2);
  const size_t gb2 = ga0 + (size_t)128 * (HID * 2);
  const int lb0 = wave * 512;               // LDS dest (elements); HW adds lane*16B
  const int lb1 = 2048 + wave * 512;
  const int lb2 = 4096 + wave * 512;

  f32x4 acc[4][6];
#pragma unroll
  for (int i = 0; i < 4; ++i)
#pragma unroll
    for (int j = 0; j < 6; ++j) acc[i][j] = f32x4{0.f, 0.f, 0.f, 0.f};

  auto stage = [&](int bufi, int k0) {      // 5 loads per thread per tile
    const size_t kb = (size_t)k0 * 2;
    gll16(Ab + ga0 + kb, &Ash[bufi][lb0]);
    gll16(Ab + ga1 + kb, &Ash[bufi][lb1]);
    gll16(Bb + ga0 + kb, &Bsh[bufi][lb0]);
    gll16(Bb + ga1 + kb, &Bsh[bufi][lb1]);
    gll16(Bb + gb2 + kb, &Bsh[bufi][lb2]);
  };
  auto compute = [&](int bufi) {
    s16x8 af[4], bfr[6];
#pragma unroll
    for (int i = 0; i < 4; ++i)
      af[i] = *(const s16x8*)(&Ash[bufi][(wr * 64 + i * 16 + l15) * 32 + quad * 8]);
#pragma unroll
    for (int j = 0; j < 6; ++j)
      bfr[j] = *(const s16x8*)(&Bsh[bufi][(wc * 96 + j * 16 + l15) * 32 + quad * 8]);
#pragma unroll
    for (int i = 0; i < 4; ++i)
#pragma unroll
      for (int j = 0; j < 6; ++j)
        acc[i][j] = __builtin_amdgcn_mfma_f32_16x16x32_bf16(af[i], bfr[j], acc[i][j], 0, 0, 0);
  };

  // prologue: tiles 0..2 in flight (15 outstanding/wave)
  stage(0, 0);
  stage(1, 32);
  stage(2, 64);
  int cur = 0, pf = 3;
  const int NT = HID / 32;                  // 32
  for (int t = 0; t < NT - 3; ++t) {        // t = 0..28
    WAITBAR(10);                            // tile t landed; t+1,t+2 stay in flight
    stage(pf, (t + 3) * 32);
    compute(cur);
    cur = (cur + 1) & 3;
    pf  = (pf + 1) & 3;
  }
  WAITBAR(10); compute(cur); cur = (cur + 1) & 3;   // t = NT-3
  WAITBAR(5);  compute(cur); cur = (cur + 1) & 3;   // t = NT-2
  WAITBAR(0);  compute(cur);                        // t = NT-1

  // epilogue: 16-col groups never straddle a 1024 boundary -> mat uniform per j
  const int rbase = bm + wr * 64;
#pragma unroll
  for (int j = 0; j < 6; ++j) {
    const int cg  = bn + wc * 96 + j * 16;  // group start (multiple of 16)
    const int mat = cg >> 10;               // 0=Q 1=K 2=V
    const int coln = (cg & 1023) + l15;     // column within matrix
    const int head = coln >> 6, d = coln & 63;
    if (mat == 2) {
      // V: f16, transposed [B,NH,D,T]; 4 consecutive t per lane = 8B store
      const float bb = bv[coln];
#pragma unroll
      for (int i = 0; i < 4; ++i) {
        const int row0 = rbase + i * 16 + quad * 4;
        const int bI = row0 >> 11, t0 = row0 & 2047;
        unsigned short o[4];
#pragma unroll
        for (int r = 0; r < 4; ++r) {
          _Float16 hv = (_Float16)(acc[i][j][r] + bb);
          o[r] = __builtin_bit_cast(unsigned short, hv);
        }
        *(s16x4*)(vto + ((size_t)((bI * NH + head) * HD + d)) * TSEQ + t0) = *(const s16x4*)o;
      }
    } else {
      unsigned short* dst = (mat == 0) ? qo : ko;
      const float bb = (mat == 0) ? bq[coln] : bk[coln] * KSCALE;
#pragma unroll
      for (int i = 0; i < 4; ++i) {
#pragma unroll
        for (int r = 0; r < 4; ++r) {
          const int row = rbase + i * 16 + quad * 4 + r;
          const int bI = row >> 11, t = row & 2047;
          dst[(((size_t)(bI * NH + head) * TSEQ) + t) * HD + d] = f2bf(acc[i][j][r] + bb);
        }
      }
    }
  }
}

// ---------------- Output projection: 128x64 tile, 5-ring depth-4, XCD swizzle ----------------
__global__ __launch_bounds__(256) void gemm_out(
    const unsigned short* __restrict__ ctx, const unsigned short* __restrict__ wo,
    const float* __restrict__ bo, const float* __restrict__ hres,
    float* __restrict__ outf) {
  __shared__ unsigned short Ash[5][128 * 32];   // 5 x 8 KB
  __shared__ unsigned short Bsh[5][64 * 32];    // 5 x 4 KB  (total 60 KB)
  const int tid = threadIdx.x, lane = tid & 63, wave = tid >> 6;
  const int l15 = lane & 15, quad = lane >> 4;
  const int wr = wave >> 1, wc = wave & 1;      // each wave: 64 rows x 32 cols
  const int bid = blockIdx.y * 16 + blockIdx.x;       // 0..511
  const int swz = (bid & 7) * 64 + (bid >> 3);
  const int bn = (swz & 15) * 64, bm = (swz >> 4) * 128;
  const char* Ab = (const char*)(ctx + (size_t)bm * HID);
  const char* Bb = (const char*)(wo + (size_t)bn * HID);
  const int off = tid * 16;
  const int r0 = off >> 6, c0 = off & 63;
  const size_t ga0 = (size_t)r0 * (HID * 2) + c0;
  const size_t ga1 = ga0 + (size_t)64 * (HID * 2);
  const int lb0 = wave * 512, lb1 = 2048 + wave * 512;

  f32x4 acc[4][2];
#pragma unroll
  for (int i = 0; i < 4; ++i)
#pragma unroll
    for (int j = 0; j < 2; ++j) acc[i][j] = f32x4{0.f, 0.f, 0.f, 0.f};

  auto stage = [&](int bufi, int k0) {
    const size_t kb = (size_t)k0 * 2;
    gll16(Ab + ga0 + kb, &Ash[bufi][lb0]);
    gll16(Ab + ga1 + kb, &Ash[bufi][lb1]);
    gll16(Bb + ga0 + kb, &Bsh[bufi][lb0]);   // 64x32 B-tile = exactly one issue
  };
  auto compute = [&](int bufi) {
    s16x8 af[4], bfr[2];
#pragma unroll
    for (int i = 0; i < 4; ++i)
      af[i] = *(const s16x8*)(&Ash[bufi][(wr * 64 + i * 16 + l15) * 32 + quad * 8]);
#pragma unroll
    for (int j = 0; j < 2; ++j)
      bfr[j] = *(const s16x8*)(&Bsh[bufi][(wc * 32 + j * 16 + l15) * 32 + quad * 8]);
#pragma unroll
    for (int i = 0; i < 4; ++i)
#pragma unroll
      for (int j = 0; j < 2; ++j)
        acc[i][j] = __builtin_amdgcn_mfma_f32_16x16x32_bf16(af[i], bfr[j], acc[i][j], 0, 0, 0);
  };

  stage(0, 0);
  stage(1, 32);
  stage(2, 64);
  stage(3, 96);
  int cur = 0, pf = 4;
  const int NT = HID / 32;
  for (int t = 0; t < NT - 4; ++t) {
    WAITBAR(9);                             // 3 loads/tile: tile t home, 3 tiles in flight
    stage(pf, (t + 4) * 32);
    compute(cur);
    cur = (cur == 4) ? 0 : cur + 1;
    pf  = (pf  == 4) ? 0 : pf + 1;
  }
  WAITBAR(9); compute(cur); cur = (cur == 4) ? 0 : cur + 1;    // t = NT-4
  WAITBAR(6); compute(cur); cur = (cur == 4) ? 0 : cur + 1;    // t = NT-3
  WAITBAR(3); compute(cur); cur = (cur == 4) ? 0 : cur + 1;    // t = NT-2
  WAITBAR(0); compute(cur);                                    // t = NT-1

#pragma unroll
  for (int j = 0; j < 2; ++j) {
    const int col = bn + wc * 32 + j * 16 + l15;
    const float bb = bo[col];
#pragma unroll
    for (int i = 0; i < 4; ++i) {
#pragma unroll
      for (int r = 0; r < 4; ++r) {
        const int row = bm + wr * 64 + i * 16 + quad * 4 + r;
        const size_t o = (size_t)row * HID + col;
        outf[o] = acc[i][j][r] + bb + hres[o];
      }
    }
  }
}

// ---------------- Flash attention: S^T form, K=32 PV, 3-buffer 1-barrier pipeline ----------------
// R8/R9-proven configuration (45.4/48.0 us). 2 blocks/CU (register-bound — R10 showed
// forcing 4 waves/EU spills). Per iter: wlds(t+1); sync; ldregs(t+2); QK^T(t+1);
// PV(t) || exp(t+1). rsum via ones-row MFMA. setprio(1) around MFMA clusters (T5).
__global__ __launch_bounds__(256, 2) void attn_k(
    const unsigned short* __restrict__ qb, const unsigned short* __restrict__ kb,
    const unsigned short* __restrict__ vt, unsigned short* __restrict__ ctx,
    int ntiles) {
  __shared__ unsigned short Ksh[3][64 * 72];   // bf16 [key][d], 3-ring
  __shared__ unsigned short Vsh[3][64 * 72];   // f16  [d][key-permuted], 3-ring

  const int tid = threadIdx.x, lane = tid & 63, wave = tid >> 6;
  const int l15 = lane & 15, quad = lane >> 4;
  const int b = blockIdx.z;
  const int h = blockIdx.y, qt = blockIdx.x;
  const size_t ho = ((size_t)(b * NH + h)) * TSEQ * HD;
  const unsigned short* Qh = qb + ho;
  const unsigned short* Kh = kb + ho;
  const unsigned short* Vh = vt + ho;
  const int q0 = qt * 128 + wave * 32;

  s16x8 qf[2][2];
#pragma unroll
  for (int s = 0; s < 2; ++s)
#pragma unroll
    for (int ks = 0; ks < 2; ++ks)
      qf[s][ks] = *(const s16x8*)(Qh + (size_t)(q0 + s * 16 + l15) * HD + ks * 32 + quad * 8);

  f32x4 accO[4][2];   // O^T: [d-strip n2][q-col s], lane=(d=quad*4+r, q=l15)
  f32x4 accR[2];      // ones-row PV: every lane ends with full key-sum for q=l15
#pragma unroll
  for (int n2 = 0; n2 < 4; ++n2)
#pragma unroll
    for (int s = 0; s < 2; ++s) accO[n2][s] = f32x4{0.f, 0.f, 0.f, 0.f};
  accR[0] = accR[1] = f32x4{0.f, 0.f, 0.f, 0.f};
  const f16x8 vones = {(_Float16)1.f, (_Float16)1.f, (_Float16)1.f, (_Float16)1.f,
                       (_Float16)1.f, (_Float16)1.f, (_Float16)1.f, (_Float16)1.f};

  const int sr = tid >> 3, sc = (tid & 7) * 8;
  // V permuted write base: c = key-chunk index 0..7, keys 8c..8c+7 ->
  // two 4-key runs at vwb and vwb+8 (verified element-wise, R6-passing)
  const int c = tid & 7;
  const int vwb = (c >> 2) * 32 + (c & 1) * 16 + ((c & 3) >> 1) * 4;
  s16x8 kreg[2], vreg[2];

  auto ldregs = [&](int kt) {
    const int k0n = kt * 64;
#pragma unroll
    for (int hf = 0; hf < 2; ++hf) {
      kreg[hf] = *(const s16x8*)(Kh + (size_t)(k0n + sr + hf * 32) * HD + sc);
      vreg[hf] = *(const s16x8*)(Vh + (size_t)(sr + hf * 32) * TSEQ + k0n + sc);
    }
  };
  auto wlds = [&](int bi) {
#pragma unroll
    for (int hf = 0; hf < 2; ++hf) {
      *(s16x8*)(Ksh[bi] + (sr + hf * 32) * 72 + sc) = kreg[hf];
      const s16x4* vh = (const s16x4*)&vreg[hf];
      *(s16x4*)(Vsh[bi] + (sr + hf * 32) * 72 + vwb)     = vh[0];
      *(s16x4*)(Vsh[bi] + (sr + hf * 32) * 72 + vwb + 8) = vh[1];
    }
  };

  f32x4 accS[2][4];
  f16x4 pP[2][4];

  auto qkt = [&](int bi) {
#pragma unroll
    for (int s = 0; s < 2; ++s)
#pragma unroll
      for (int n = 0; n < 4; ++n) accS[s][n] = f32x4{0.f, 0.f, 0.f, 0.f};
    __builtin_amdgcn_s_setprio(1);
#pragma unroll
    for (int ks = 0; ks < 2; ++ks) {
#pragma unroll
      for (int n = 0; n < 4; ++n) {
        s16x8 kf = *(const s16x8*)(Ksh[bi] + (n * 16 + l15) * 72 + ks * 32 + quad * 8);
#pragma unroll
        for (int s = 0; s < 2; ++s)
          accS[s][n] = __builtin_amdgcn_mfma_f32_16x16x32_bf16(kf, qf[s][ks], accS[s][n], 0, 0, 0);
      }
    }
    __builtin_amdgcn_s_setprio(0);
  };
  auto expp = [&]() {   // accS -> pP (f16 pairs); rsum handled by ones-row MFMA
#pragma unroll
    for (int s = 0; s < 2; ++s)
#pragma unroll
      for (int n = 0; n < 4; ++n) {
        float e0 = __builtin_amdgcn_exp2f(accS[s][n][0]);
        float e1 = __builtin_amdgcn_exp2f(accS[s][n][1]);
        float e2 = __builtin_amdgcn_exp2f(accS[s][n][2]);
        float e3 = __builtin_amdgcn_exp2f(accS[s][n][3]);
        f16x2 lo = __builtin_bit_cast(f16x2, __builtin_amdgcn_cvt_pkrtz(e0, e1));
        f16x2 hi = __builtin_bit_cast(f16x2, __builtin_amdgcn_cvt_pkrtz(e2, e3));
        pP[s][n] = f16x4{lo[0], lo[1], hi[0], hi[1]};
      }
  };
  auto pv = [&](int bi) {   // K=32 full-rate f16 MFMA + ones-row rsum
    __builtin_amdgcn_s_setprio(1);
#pragma unroll
    for (int kk = 0; kk < 2; ++kk) {
      union { f16x4 h[2]; f16x8 v8; } u0, u1;
      u0.h[0] = pP[0][2 * kk]; u0.h[1] = pP[0][2 * kk + 1];
      u1.h[0] = pP[1][2 * kk]; u1.h[1] = pP[1][2 * kk + 1];
      accR[0] = __builtin_amdgcn_mfma_f32_16x16x32_f16(vones, u0.v8, accR[0], 0, 0, 0);
      accR[1] = __builtin_amdgcn_mfma_f32_16x16x32_f16(vones, u1.v8, accR[1], 0, 0, 0);
#pragma unroll
      for (int n2 = 0; n2 < 4; ++n2) {
        f16x8 vA = *(const f16x8*)(Vsh[bi] + (n2 * 16 + l15) * 72 + kk * 32 + quad * 8);
        accO[n2][0] = __builtin_amdgcn_mfma_f32_16x16x32_f16(vA, u0.v8, accO[n2][0], 0, 0, 0);
        accO[n2][1] = __builtin_amdgcn_mfma_f32_16x16x32_f16(vA, u1.v8, accO[n2][1], 0, 0, 0);
      }
    }
    __builtin_amdgcn_s_setprio(0);
  };

  // prologue
  ldregs(0);
  wlds(0);
  __syncthreads();
  if (ntiles > 1) ldregs(1);
  qkt(0);
  expp();

  int b0 = 0, b1 = 1;
  for (int t = 0; t < ntiles - 1; ++t) {
    wlds(b1);                     // stage tile t+1 (regs loaded at iter t-1)
    __syncthreads();              // writes visible; 3-ring guards reuse
    if (t + 2 < ntiles) ldregs(t + 2);
    qkt(b1);                      // accS(t+1)  [MFMA]
    pv(b0);                       // PV(t) w/ pP(t) [MFMA] - independent of accS
    expp();                       // exp(t+1) -> pP [VALU] - overlaps PV issue
    b0 = b1; b1 = (b1 == 2) ? 0 : b1 + 1;
  }
  pv(b0);                         // PV(ntiles-1)

  float rsum[2] = {accR[0][0], accR[1][0]};   // all lanes hold their q's full sum

#pragma unroll
  for (int s = 0; s < 2; ++s) {
    const int t = q0 + s * 16 + l15;
    const float inv = 1.f / rsum[s];
#pragma unroll
    for (int n2 = 0; n2 < 4; ++n2) {
      const int d0 = n2 * 16 + quad * 4;
      unsigned short o[4];
#pragma unroll
      for (int r = 0; r < 4; ++r) o[r] = f2bf(accO[n2][s][r] * inv);
      *(s16x4*)(ctx + ((size_t)(b * TSEQ + t)) * HID + h * HD + d0) = *(const s16x4*)o;
    }
  }
}

// ---------------- In-place LayerNorm over rows of 1024 ----------------
__global__ __launch_bounds__(256) void ln_k(float* __restrict__ io,
                                            const float* __restrict__ gamma,
                                            const float* __restrict__ beta) {
  const int row = blockIdx.x, tid = threadIdx.x;
  float x[4]; float s = 0.f, s2 = 0.f;
#pragma unroll
  for (int i = 0; i < 4; ++i) {
    x[i] = io[(size_t)row * HID + tid + i * 256];
    s += x[i]; s2 += x[i] * x[i];
  }
#pragma unroll
  for (int off = 1; off < 64; off <<= 1) {
    s  += __shfl_xor(s, off, 64);
    s2 += __shfl_xor(s2, off, 64);
  }
  __shared__ float red[8];
  const int wave = tid >> 6;
  if ((tid & 63) == 0) { red[wave] = s; red[wave + 4] = s2; }
  __syncthreads();
  s  = red[0] + red[1] + red[2] + red[3];
  s2 = red[4] + red[5] + red[6] + red[7];
  const float mean = s * (1.f / HID);
  const float var  = s2 * (1.f / HID) - mean * mean;
  const float rstd = rsqrtf(var + 1e-6f);
#pragma unroll
  for (int i = 0; i < 4; ++i) {
    const int col = tid + i * 256;
    io[(size_t)row * HID + col] = (x[i] - mean) * rstd * gamma[col] + beta[col];
  }
}

extern "C" void kernel_launch(void* const* d_in, const int* in_sizes, int n_in,
                              void* d_out, int out_size, void* d_ws, size_t ws_size,
                              hipStream_t stream) {
  const float* h    = (const float*)d_in[0];
  const float* Wq   = (const float*)d_in[1];
  const float* bq   = (const float*)d_in[2];
  const float* Wk   = (const float*)d_in[3];
  const float* bk   = (const float*)d_in[4];
  const float* Wv   = (const float*)d_in[5];
  const float* bv   = (const float*)d_in[6];
  const float* Wo   = (const float*)d_in[7];
  const float* bo   = (const float*)d_in[8];
  const float* gamma = (const float*)d_in[9];
  const float* beta  = (const float*)d_in[10];
  float* out = (float*)d_out;

  unsigned short* hb   = (unsigned short*)d_ws;   // bf16 h; dead after gemm_qkv -> reused as ctx
  unsigned short* wqb  = hb  + 4194304;           // 4 weights contiguous (Wq|Wk|Wv|Wo)
  unsigned short* wkb  = wqb + 1048576;
  unsigned short* wvb  = wkb + 1048576;
  unsigned short* wob  = wvb + 1048576;
  unsigned short* qb   = wob + 1048576;           // bf16 [B,NH,T,D]
  unsigned short* kb   = qb  + 4194304;
  unsigned short* vtf  = kb  + 4194304;           // f16 [B,NH,D,T], written by gemm_qkv directly
  unsigned short* ctxb = hb;                      // ctx aliases dead hb

  cast_all_k<<<8192, 256, 0, stream>>>(h, Wq, Wk, Wv, Wo, hb, wqb);
  gemm_qkv<<<dim3(16, 32), 256, 0, stream>>>(hb, wqb, bq, bk, bv, qb, kb, vtf);
  attn_k<<<dim3(TSEQ / 128, NH, BATCH), 256, 0, stream>>>(qb, kb, vtf, ctxb, 32);
  gemm_out<<<dim3(16, 32), 256, 0, stream>>>(ctxb, wob, bo, h, out);
  ln_k<<<4096, 256, 0, stream>>>(out, gamma, beta);
}